// Round 1
// 830.918 us; speedup vs baseline: 1.3312x; 1.3312x over previous
//
#include <hip/hip_runtime.h>
#include <hip/hip_fp8.h>

typedef unsigned char u8;
typedef float v2f __attribute__((ext_vector_type(2)));

#define SCAN_B 256

static __device__ __forceinline__ float fp8_to_f32(u8 b) {
    __hip_fp8_e4m3 t;
    t.__x = (__hip_fp8_storage_t)b;
    return (float)t;
}
static __device__ __forceinline__ u8 f32_to_fp8(float v) {
    __hip_fp8_e4m3 t(v);
    return (u8)t.__x;
}

// hardware packed fp8->f32 (2 values per instruction); exact conversion either way
template <bool HI>
static __device__ __forceinline__ v2f pk2(unsigned w) {
#if __has_builtin(__builtin_amdgcn_cvt_pk_f32_fp8)
    return __builtin_amdgcn_cvt_pk_f32_fp8((int)w, HI);
#else
    v2f r;
    r.x = fp8_to_f32(HI ? (u8)(w >> 16) : (u8)(w));
    r.y = fp8_to_f32(HI ? (u8)(w >> 24) : (u8)(w >> 8));
    return r;
#endif
}

// ---------------- edge-format probe: int64-as-int32 (odd words zero) vs int32 ----------------
__global__ void detect_kernel(const int* __restrict__ edges, int* __restrict__ flag) {
    __shared__ int cnt[256];
    int t = threadIdx.x;
    int c = 0;
    for (int i = t; i < 32768; i += 256)
        if (edges[2 * i + 1] != 0) c++;
    cnt[t] = c;
    __syncthreads();
    for (int off = 128; off > 0; off >>= 1) {
        if (t < off) cnt[t] += cnt[t + off];
        __syncthreads();
    }
    if (t == 0) flag[0] = (cnt[0] < 8) ? 2 : 1;
}

// ---------------- degree histogram ----------------
__global__ void count_deg_kernel(const int* __restrict__ edges, const int* __restrict__ flag,
                                 int* __restrict__ deg, int E) {
    int e = blockIdx.x * blockDim.x + threadIdx.x;
    if (e >= E) return;
    int s = flag[0];
    int d = edges[E * s + e * s];     // dst[e]
    atomicAdd(&deg[d], 1);
}

// ---------------- scan phase 1 ----------------
__global__ void scan_phase1(const int* __restrict__ deg, int* __restrict__ row_ptr,
                            int* __restrict__ bsum, int n) {
    __shared__ int sh[2][SCAN_B];
    int t = threadIdx.x;
    int gi = blockIdx.x * SCAN_B + t;
    int v = (gi < n) ? deg[gi] : 0;
    int src = 0;
    sh[0][t] = v;
    __syncthreads();
    for (int off = 1; off < SCAN_B; off <<= 1) {
        int x = sh[src][t] + ((t >= off) ? sh[src][t - off] : 0);
        sh[src ^ 1][t] = x;
        src ^= 1;
        __syncthreads();
    }
    int incl = sh[src][t];
    if (gi < n) row_ptr[gi] = incl - v;
    if (t == SCAN_B - 1) bsum[blockIdx.x] = incl;
}

// ---------------- scan phase 2 ----------------
__global__ void scan_phase2(int* __restrict__ bsum, int nb) {
    __shared__ int sh[1024];
    int t = threadIdx.x;
    sh[t] = (t < nb) ? bsum[t] : 0;
    __syncthreads();
    if (t == 0) {
        int acc = 0;
        for (int i = 0; i < nb; ++i) { int x = sh[i]; sh[i] = acc; acc += x; }
    }
    __syncthreads();
    if (t < nb) bsum[t] = sh[t];
}

// ---------------- scan phase 3 ----------------
__global__ void scan_phase3(const int* __restrict__ deg, const int* __restrict__ bsum,
                            int* __restrict__ row_ptr, int* __restrict__ cursor,
                            float* __restrict__ dis, int n, int E) {
    int gi = blockIdx.x * SCAN_B + threadIdx.x;
    if (gi < n) {
        int e = row_ptr[gi] + bsum[blockIdx.x];
        row_ptr[gi] = e;
        cursor[gi]  = e;
        int d = deg[gi];
        dis[gi] = (d > 0) ? rsqrtf((float)d) : 0.0f;
    }
    if (gi == 0) row_ptr[n] = E;
}

// ---------------- scatter edges into CSR: (col, weight) packed int2 ----------------
__global__ void scatter_kernel(const int* __restrict__ edges, const int* __restrict__ flag,
                               const float* __restrict__ dis, int* __restrict__ cursor,
                               int2* __restrict__ cw, int E) {
    int e = blockIdx.x * blockDim.x + threadIdx.x;
    if (e >= E) return;
    int s = flag[0];
    int sv = edges[e * s];            // src[e]
    int dv = edges[E * s + e * s];    // dst[e]
    float w = dis[sv] * dis[dv];
    int pos = atomicAdd(&cursor[dv], 1);
    cw[pos] = make_int2(sv, __float_as_int(w));
}

// ---------------- init: x0 (fp8, in d_out scratch) = emb ----------------
__global__ void init_kernel(const float* __restrict__ eu, const float* __restrict__ ei,
                            u8* __restrict__ x0, long NU64, long tot) {
    long i = (long)blockIdx.x * blockDim.x + threadIdx.x;
    if (i >= tot) return;
    float v = (i < NU64) ? eu[i] : ei[i - NU64];
    x0[i] = f32_to_fp8(v);
}

// ---------------- SpMM layer: one wave per dst node ----------------
// Lane layout: g = lane>>4 selects one of 4 edges processed per step,
//              q = lane&15 selects dim-quarter (dims 4q..4q+3, one dword of fp8).
// Each gather instruction therefore serves 4 edges (256B across 4 lines) instead
// of 1 edge (64B, 64 byte-granular addresses) -> 4x fewer address slots per edge.
__global__ void spmm_kernel(const int* __restrict__ row_ptr, const int2* __restrict__ cw,
                            const u8* __restrict__ xin, u8* __restrict__ xout, int n) {
    int wave = (blockIdx.x * blockDim.x + threadIdx.x) >> 6;
    int lane = threadIdx.x & 63;
    if (wave >= n) return;
    int beg = row_ptr[wave], end = row_ptr[wave + 1];
    int g = lane >> 4;
    int q = lane & 15;

    float ax = 0.0f, ay = 0.0f, az = 0.0f, aw = 0.0f;

    // 8 edges in flight per iteration (chunks A and B of 4 edges each)
    for (int iA = beg + g; iA < end; iA += 8) {
        int iB = iA + 4;
        bool vB = iB < end;

        int2 ca = cw[iA];
        int2 cb = cw[vB ? iB : iA];

        unsigned dA = *(const unsigned*)(xin + ((long)ca.x << 6) + (q << 2));
        unsigned dB = *(const unsigned*)(xin + ((long)cb.x << 6) + (q << 2));

        float wA = __int_as_float(ca.y);
        float wB = vB ? __int_as_float(cb.y) : 0.0f;

        v2f a01 = pk2<false>(dA);
        v2f a23 = pk2<true>(dA);
        v2f b01 = pk2<false>(dB);
        v2f b23 = pk2<true>(dB);

        ax = fmaf(wA, a01.x, ax); ay = fmaf(wA, a01.y, ay);
        az = fmaf(wA, a23.x, az); aw = fmaf(wA, a23.y, aw);
        ax = fmaf(wB, b01.x, ax); ay = fmaf(wB, b01.y, ay);
        az = fmaf(wB, b23.x, az); aw = fmaf(wB, b23.y, aw);
    }

    // reduce across the 4 edge-groups: lanes differing in bits 4,5 share the same q
    ax += __shfl_xor(ax, 16); ay += __shfl_xor(ay, 16);
    az += __shfl_xor(az, 16); aw += __shfl_xor(aw, 16);
    ax += __shfl_xor(ax, 32); ay += __shfl_xor(ay, 32);
    az += __shfl_xor(az, 32); aw += __shfl_xor(aw, 32);

    if (g == 0) {
        unsigned ow = (unsigned)f32_to_fp8(ax)
                    | ((unsigned)f32_to_fp8(ay) << 8)
                    | ((unsigned)f32_to_fp8(az) << 16)
                    | ((unsigned)f32_to_fp8(aw) << 24);
        *(unsigned*)(xout + ((long)wave << 6) + (q << 2)) = ow;
    }
}

// ---------------- epilogue: out = (emb + x1+x2+x3+x4)/25, plus orig copies ----------------
__global__ void final_kernel(const u8* __restrict__ x1, const u8* __restrict__ x2,
                             const u8* __restrict__ x3, const u8* __restrict__ x4,
                             const float* __restrict__ eu, const float* __restrict__ ei,
                             float* __restrict__ out, long NU64, long NI64) {
    long i = (long)blockIdx.x * blockDim.x + threadIdx.x;
    if (i >= NU64 + NI64) return;
    float base = (i < NU64) ? eu[i] : ei[i - NU64];
    float s = base + fp8_to_f32(x1[i]) + fp8_to_f32(x2[i])
                   + fp8_to_f32(x3[i]) + fp8_to_f32(x4[i]);
    float v = s * (1.0f / 25.0f);
    if (i < NU64) {
        out[i] = v;                              // users_final [0, NU64)
        out[NU64 + i] = base;                    // users_orig  [NU64, 2NU64)
    } else {
        long j = i - NU64;
        out[2 * NU64 + j] = v;                   // items_final [2NU64, 2NU64+NI64)
        out[2 * NU64 + NI64 + j] = base;         // items_orig  [2NU64+NI64, end)
    }
}

extern "C" void kernel_launch(void* const* d_in, const int* in_sizes, int n_in,
                              void* d_out, int out_size, void* d_ws, size_t ws_size,
                              hipStream_t stream) {
    const float* eu = (const float*)d_in[0];
    const float* ei = (const float*)d_in[1];
    const int* edges = (const int*)d_in[2];
    float* out = (float*)d_out;

    const int NU = in_sizes[0] / 64;
    const int NI = in_sizes[1] / 64;
    const int N  = NU + NI;
    const int E  = in_sizes[2] / 2;

    // workspace carve-up (256B aligned) — ~73 MB total (proven footprint)
    char* w = (char*)d_ws;
    size_t off = 0;
    auto alloc = [&](size_t bytes) -> void* {
        void* p = w + off;
        off += (bytes + 255) & ~(size_t)255;
        return p;
    };
    int*   flag    = (int*)  alloc(256);
    int*   deg     = (int*)  alloc((size_t)N * 4);
    int*   row_ptr = (int*)  alloc((size_t)(N + 1) * 4);
    int*   cursor  = (int*)  alloc((size_t)N * 4);
    float* dis     = (float*)alloc((size_t)N * 4);
    int*   bsum    = (int*)  alloc(1024 * 4);
    int2*  cw      = (int2*) alloc((size_t)E * 8);
    const long NU64 = (long)NU * 64, NI64 = (long)NI * 64;
    const long tot = NU64 + NI64;          // = N*64
    u8* x1 = (u8*)alloc((size_t)tot);      // 9.6 MB each
    u8* x2 = (u8*)alloc((size_t)tot);
    u8* x3 = (u8*)alloc((size_t)tot);
    u8* x4 = (u8*)alloc((size_t)tot);

    // x0 scratch lives in d_out (9.6 MB << 76.8 MB); consumed by layer 1, dead before final.
    u8* x0 = (u8*)out;

    const int nb = (N + SCAN_B - 1) / SCAN_B;   // 586 <= 1024

    detect_kernel<<<1, 256, 0, stream>>>(edges, flag);
    hipMemsetAsync(deg, 0, (size_t)N * 4, stream);
    count_deg_kernel<<<(E + 255) / 256, 256, 0, stream>>>(edges, flag, deg, E);
    scan_phase1<<<nb, SCAN_B, 0, stream>>>(deg, row_ptr, bsum, N);
    scan_phase2<<<1, 1024, 0, stream>>>(bsum, nb);
    scan_phase3<<<nb, SCAN_B, 0, stream>>>(deg, bsum, row_ptr, cursor, dis, N, E);
    scatter_kernel<<<(E + 255) / 256, 256, 0, stream>>>(edges, flag, dis, cursor, cw, E);

    init_kernel<<<(int)((tot + 255) / 256), 256, 0, stream>>>(eu, ei, x0, NU64, tot);

    const int nblk = (N + 3) / 4;  // 4 waves (rows) per 256-thread block
    spmm_kernel<<<nblk, 256, 0, stream>>>(row_ptr, cw, x0, x1, N);
    spmm_kernel<<<nblk, 256, 0, stream>>>(row_ptr, cw, x1, x2, N);
    spmm_kernel<<<nblk, 256, 0, stream>>>(row_ptr, cw, x2, x3, N);
    spmm_kernel<<<nblk, 256, 0, stream>>>(row_ptr, cw, x3, x4, N);

    final_kernel<<<(int)((tot + 255) / 256), 256, 0, stream>>>(x1, x2, x3, x4, eu, ei,
                                                               out, NU64, NI64);
}

// Round 2
// 766.178 us; speedup vs baseline: 1.4437x; 1.0845x over previous
//
#include <hip/hip_runtime.h>
#include <hip/hip_fp8.h>

typedef unsigned char u8;
typedef float v2f __attribute__((ext_vector_type(2)));

#define SCAN_B 256

// bucketed scatter params
#define NPB      128          // dst nodes per bucket
#define NPB_SH   7
#define P2_CAP   6144         // win entries per bucket (48 KB LDS); item buckets max ~5.5K
#define P1_CHUNK 8192         // edges per part1 block
#define NB_MAX   2048         // part1 LDS bucket capacity (NB=1172 for N=150K)

static __device__ __forceinline__ float fp8_to_f32(u8 b) {
    __hip_fp8_e4m3 t;
    t.__x = (__hip_fp8_storage_t)b;
    return (float)t;
}
static __device__ __forceinline__ u8 f32_to_fp8(float v) {
    __hip_fp8_e4m3 t(v);
    return (u8)t.__x;
}

// hardware packed fp8->f32 (2 values per instruction)
template <bool HI>
static __device__ __forceinline__ v2f pk2(unsigned w) {
#if __has_builtin(__builtin_amdgcn_cvt_pk_f32_fp8)
    return __builtin_amdgcn_cvt_pk_f32_fp8((int)w, HI);
#else
    v2f r;
    r.x = fp8_to_f32(HI ? (u8)(w >> 16) : (u8)(w));
    r.y = fp8_to_f32(HI ? (u8)(w >> 24) : (u8)(w >> 8));
    return r;
#endif
}

// ---------------- edge-format probe: int64-as-int32 (odd words zero) vs int32 ----------------
__global__ void detect_kernel(const int* __restrict__ edges, int* __restrict__ flag) {
    __shared__ int cnt[256];
    int t = threadIdx.x;
    int c = 0;
    for (int i = t; i < 32768; i += 256)
        if (edges[2 * i + 1] != 0) c++;
    cnt[t] = c;
    __syncthreads();
    for (int off = 128; off > 0; off >>= 1) {
        if (t < off) cnt[t] += cnt[t + off];
        __syncthreads();
    }
    if (t == 0) flag[0] = (cnt[0] < 8) ? 2 : 1;
}

// ---------------- degree histogram ----------------
__global__ void count_deg_kernel(const int* __restrict__ edges, const int* __restrict__ flag,
                                 int* __restrict__ deg, int E) {
    int e = blockIdx.x * blockDim.x + threadIdx.x;
    if (e >= E) return;
    int s = flag[0];
    int d = edges[(long)E * s + (long)e * s];     // dst[e]
    atomicAdd(&deg[d], 1);
}

// ---------------- scan phase 1 ----------------
__global__ void scan_phase1(const int* __restrict__ deg, int* __restrict__ row_ptr,
                            int* __restrict__ bsum, int n) {
    __shared__ int sh[2][SCAN_B];
    int t = threadIdx.x;
    int gi = blockIdx.x * SCAN_B + t;
    int v = (gi < n) ? deg[gi] : 0;
    int src = 0;
    sh[0][t] = v;
    __syncthreads();
    for (int off = 1; off < SCAN_B; off <<= 1) {
        int x = sh[src][t] + ((t >= off) ? sh[src][t - off] : 0);
        sh[src ^ 1][t] = x;
        src ^= 1;
        __syncthreads();
    }
    int incl = sh[src][t];
    if (gi < n) row_ptr[gi] = incl - v;
    if (t == SCAN_B - 1) bsum[blockIdx.x] = incl;
}

// ---------------- scan phase 2 ----------------
__global__ void scan_phase2(int* __restrict__ bsum, int nb) {
    __shared__ int sh[1024];
    int t = threadIdx.x;
    sh[t] = (t < nb) ? bsum[t] : 0;
    __syncthreads();
    if (t == 0) {
        int acc = 0;
        for (int i = 0; i < nb; ++i) { int x = sh[i]; sh[i] = acc; acc += x; }
    }
    __syncthreads();
    if (t < nb) bsum[t] = sh[t];
}

// ---------------- scan phase 3 ----------------
__global__ void scan_phase3(const int* __restrict__ deg, const int* __restrict__ bsum,
                            int* __restrict__ row_ptr, int* __restrict__ cursor,
                            float* __restrict__ dis, int n, int E) {
    int gi = blockIdx.x * SCAN_B + threadIdx.x;
    if (gi < n) {
        int e = row_ptr[gi] + bsum[blockIdx.x];
        row_ptr[gi] = e;
        cursor[gi]  = e;
        int d = deg[gi];
        dis[gi] = (d > 0) ? rsqrtf((float)d) : 0.0f;
    }
    if (gi == 0) row_ptr[n] = E;
}

// ---------------- gcur init: bucket staging cursors = CSR bucket bases ----------------
__global__ void gcur_init_kernel(const int* __restrict__ row_ptr, int* __restrict__ gcur,
                                 int n, int NB) {
    int b = blockIdx.x * blockDim.x + threadIdx.x;
    if (b < NB) gcur[b] = row_ptr[min(b << NPB_SH, n)];
}

// ---------------- part1: partition edges into dst-buckets (time-local runs) ----------------
// Each block claims one contiguous chunk per bucket (one global atomic per (block,bucket)),
// then streams (src,dst) into bucket-contiguous staging. Stores from a block hit ~NB short
// runs that stay L2-resident until full -> near-full-line writebacks instead of 64B/edge.
__global__ void part1_kernel(const int* __restrict__ edges, const int* __restrict__ flag,
                             int* __restrict__ gcur, int2* __restrict__ staging,
                             int E, int NB) {
    __shared__ int lcount[NB_MAX];
    __shared__ int lbase[NB_MAX];
    int t = threadIdx.x;
    int s = flag[0];
    long e0 = (long)blockIdx.x * P1_CHUNK;
    for (int b = t; b < NB; b += 256) lcount[b] = 0;
    __syncthreads();
    for (int j = 0; j < P1_CHUNK / 256; ++j) {
        long e = e0 + j * 256 + t;
        if (e < E) {
            int dv = edges[(long)E * s + e * s];
            atomicAdd(&lcount[dv >> NPB_SH], 1);
        }
    }
    __syncthreads();
    for (int b = t; b < NB; b += 256) {
        int c = lcount[b];
        lbase[b] = (c > 0) ? atomicAdd(&gcur[b], c) : 0;
        lcount[b] = 0;          // reuse as block-local cursor
    }
    __syncthreads();
    for (int j = 0; j < P1_CHUNK / 256; ++j) {
        long e = e0 + j * 256 + t;
        if (e < E) {
            int sv = edges[e * s];
            int dv = edges[(long)E * s + e * s];
            int b = dv >> NPB_SH;
            int slot = atomicAdd(&lcount[b], 1);
            staging[lbase[b] + slot] = make_int2(sv, dv);
        }
    }
}

// ---------------- part2: per-bucket exact CSR placement, built in LDS ----------------
// One block per bucket. cw window for the bucket is assembled in LDS via LDS-atomic
// per-node cursors, then dumped with fully coalesced stores (write amplification ~1.0).
__global__ void __launch_bounds__(256) part2_kernel(
        const int* __restrict__ row_ptr, const int2* __restrict__ staging,
        const float* __restrict__ dis, int2* __restrict__ cw, int n) {
    __shared__ int2 win[P2_CAP];
    __shared__ int cur[NPB];
    int b = blockIdx.x;
    int t = threadIdx.x;
    int dlo = b << NPB_SH;
    int dhi = min(dlo + NPB, n);
    int base = row_ptr[dlo];
    int cnt = row_ptr[dhi] - base;
    if (t < NPB) {
        int node = dlo + t;
        cur[t] = (node < n) ? (row_ptr[node] - base) : 0;
    }
    __syncthreads();
    if (cnt <= P2_CAP) {
        for (int k = t; k < cnt; k += 256) {
            int2 sd = staging[base + k];
            float w = dis[sd.x] * dis[sd.y];
            int p = atomicAdd(&cur[sd.y - dlo], 1);
            win[p] = make_int2(sd.x, __float_as_int(w));
        }
        __syncthreads();
        for (int k = t; k < cnt; k += 256)
            cw[base + k] = win[k];
    } else {
        // data-dependent overflow fallback: direct stores, still within a small window
        for (int k = t; k < cnt; k += 256) {
            int2 sd = staging[base + k];
            float w = dis[sd.x] * dis[sd.y];
            int p = atomicAdd(&cur[sd.y - dlo], 1);
            cw[base + p] = make_int2(sd.x, __float_as_int(w));
        }
    }
}

// ---------------- legacy direct scatter (fallback if NB > NB_MAX) ----------------
__global__ void scatter_kernel(const int* __restrict__ edges, const int* __restrict__ flag,
                               const float* __restrict__ dis, int* __restrict__ cursor,
                               int2* __restrict__ cw, int E) {
    int e = blockIdx.x * blockDim.x + threadIdx.x;
    if (e >= E) return;
    int s = flag[0];
    int sv = edges[(long)e * s];
    int dv = edges[(long)E * s + (long)e * s];
    float w = dis[sv] * dis[dv];
    int pos = atomicAdd(&cursor[dv], 1);
    cw[pos] = make_int2(sv, __float_as_int(w));
}

// ---------------- init: x0 (fp8, in d_out scratch) = emb ----------------
__global__ void init_kernel(const float* __restrict__ eu, const float* __restrict__ ei,
                            u8* __restrict__ x0, long NU64, long tot) {
    long i = (long)blockIdx.x * blockDim.x + threadIdx.x;
    if (i >= tot) return;
    float v = (i < NU64) ? eu[i] : ei[i - NU64];
    x0[i] = f32_to_fp8(v);
}

// ---------------- SpMM layer: one wave per dst node ----------------
// Lane layout: g = lane>>4 selects one of 4 edges per step, q = lane&15 selects the
// dim-quarter (dims 4q..4q+3, one dword of fp8). Each gather serves 4 edges.
__global__ void spmm_kernel(const int* __restrict__ row_ptr, const int2* __restrict__ cw,
                            const u8* __restrict__ xin, u8* __restrict__ xout, int n) {
    int wave = (blockIdx.x * blockDim.x + threadIdx.x) >> 6;
    int lane = threadIdx.x & 63;
    if (wave >= n) return;
    int beg = row_ptr[wave], end = row_ptr[wave + 1];
    int g = lane >> 4;
    int q = lane & 15;

    float ax = 0.0f, ay = 0.0f, az = 0.0f, aw = 0.0f;

    for (int iA = beg + g; iA < end; iA += 8) {
        int iB = iA + 4;
        bool vB = iB < end;

        int2 ca = cw[iA];
        int2 cb = cw[vB ? iB : iA];

        unsigned dA = *(const unsigned*)(xin + ((long)ca.x << 6) + (q << 2));
        unsigned dB = *(const unsigned*)(xin + ((long)cb.x << 6) + (q << 2));

        float wA = __int_as_float(ca.y);
        float wB = vB ? __int_as_float(cb.y) : 0.0f;

        v2f a01 = pk2<false>(dA);
        v2f a23 = pk2<true>(dA);
        v2f b01 = pk2<false>(dB);
        v2f b23 = pk2<true>(dB);

        ax = fmaf(wA, a01.x, ax); ay = fmaf(wA, a01.y, ay);
        az = fmaf(wA, a23.x, az); aw = fmaf(wA, a23.y, aw);
        ax = fmaf(wB, b01.x, ax); ay = fmaf(wB, b01.y, ay);
        az = fmaf(wB, b23.x, az); aw = fmaf(wB, b23.y, aw);
    }

    ax += __shfl_xor(ax, 16); ay += __shfl_xor(ay, 16);
    az += __shfl_xor(az, 16); aw += __shfl_xor(aw, 16);
    ax += __shfl_xor(ax, 32); ay += __shfl_xor(ay, 32);
    az += __shfl_xor(az, 32); aw += __shfl_xor(aw, 32);

    if (g == 0) {
        unsigned ow = (unsigned)f32_to_fp8(ax)
                    | ((unsigned)f32_to_fp8(ay) << 8)
                    | ((unsigned)f32_to_fp8(az) << 16)
                    | ((unsigned)f32_to_fp8(aw) << 24);
        *(unsigned*)(xout + ((long)wave << 6) + (q << 2)) = ow;
    }
}

// ---------------- epilogue: out = (emb + x1+x2+x3+x4)/25, plus orig copies ----------------
__global__ void final_kernel(const u8* __restrict__ x1, const u8* __restrict__ x2,
                             const u8* __restrict__ x3, const u8* __restrict__ x4,
                             const float* __restrict__ eu, const float* __restrict__ ei,
                             float* __restrict__ out, long NU64, long NI64) {
    long i = (long)blockIdx.x * blockDim.x + threadIdx.x;
    if (i >= NU64 + NI64) return;
    float base = (i < NU64) ? eu[i] : ei[i - NU64];
    float s = base + fp8_to_f32(x1[i]) + fp8_to_f32(x2[i])
                   + fp8_to_f32(x3[i]) + fp8_to_f32(x4[i]);
    float v = s * (1.0f / 25.0f);
    if (i < NU64) {
        out[i] = v;
        out[NU64 + i] = base;
    } else {
        long j = i - NU64;
        out[2 * NU64 + j] = v;
        out[2 * NU64 + NI64 + j] = base;
    }
}

extern "C" void kernel_launch(void* const* d_in, const int* in_sizes, int n_in,
                              void* d_out, int out_size, void* d_ws, size_t ws_size,
                              hipStream_t stream) {
    const float* eu = (const float*)d_in[0];
    const float* ei = (const float*)d_in[1];
    const int* edges = (const int*)d_in[2];
    float* out = (float*)d_out;

    const int NU = in_sizes[0] / 64;
    const int NI = in_sizes[1] / 64;
    const int N  = NU + NI;
    const int E  = in_sizes[2] / 2;
    const int NB = (N + NPB - 1) / NPB;     // 1172 for N=150K

    // workspace carve-up (256B aligned)
    char* w = (char*)d_ws;
    size_t off = 0;
    auto alloc = [&](size_t bytes) -> void* {
        void* p = w + off;
        off += (bytes + 255) & ~(size_t)255;
        return p;
    };
    int*   flag    = (int*)  alloc(256);
    int*   deg     = (int*)  alloc((size_t)N * 4);
    int*   row_ptr = (int*)  alloc((size_t)(N + 1) * 4);
    int*   cursor  = (int*)  alloc((size_t)N * 4);
    float* dis     = (float*)alloc((size_t)N * 4);
    int*   bsum    = (int*)  alloc(1024 * 4);
    int*   gcur    = (int*)  alloc((size_t)NB * 4);
    int2*  cw      = (int2*) alloc((size_t)E * 8);
    const long NU64 = (long)NU * 64, NI64 = (long)NI * 64;
    const long tot = NU64 + NI64;          // = N*64
    u8* x1 = (u8*)alloc((size_t)tot);
    u8* x2 = (u8*)alloc((size_t)tot);
    u8* x3 = (u8*)alloc((size_t)tot);
    u8* x4 = (u8*)alloc((size_t)tot);

    // d_out scratch: x0 in [0, 9.6MB); staging (src,dst) int2 in [16MB, 48MB).
    // Both dead before final_kernel writes out (76.8 MB).
    u8*   x0      = (u8*)out;
    int2* staging = (int2*)((char*)out + ((size_t)16 << 20));

    const int nb = (N + SCAN_B - 1) / SCAN_B;

    detect_kernel<<<1, 256, 0, stream>>>(edges, flag);
    hipMemsetAsync(deg, 0, (size_t)N * 4, stream);
    count_deg_kernel<<<(E + 255) / 256, 256, 0, stream>>>(edges, flag, deg, E);
    scan_phase1<<<nb, SCAN_B, 0, stream>>>(deg, row_ptr, bsum, N);
    scan_phase2<<<1, 1024, 0, stream>>>(bsum, nb);
    scan_phase3<<<nb, SCAN_B, 0, stream>>>(deg, bsum, row_ptr, cursor, dis, N, E);

    if (NB <= NB_MAX) {
        gcur_init_kernel<<<(NB + 255) / 256, 256, 0, stream>>>(row_ptr, gcur, N, NB);
        part1_kernel<<<(E + P1_CHUNK - 1) / P1_CHUNK, 256, 0, stream>>>(edges, flag, gcur,
                                                                        staging, E, NB);
        part2_kernel<<<NB, 256, 0, stream>>>(row_ptr, staging, dis, cw, N);
    } else {
        scatter_kernel<<<(E + 255) / 256, 256, 0, stream>>>(edges, flag, dis, cursor, cw, E);
    }

    init_kernel<<<(int)((tot + 255) / 256), 256, 0, stream>>>(eu, ei, x0, NU64, tot);

    const int nblk = (N + 3) / 4;
    spmm_kernel<<<nblk, 256, 0, stream>>>(row_ptr, cw, x0, x1, N);
    spmm_kernel<<<nblk, 256, 0, stream>>>(row_ptr, cw, x1, x2, N);
    spmm_kernel<<<nblk, 256, 0, stream>>>(row_ptr, cw, x2, x3, N);
    spmm_kernel<<<nblk, 256, 0, stream>>>(row_ptr, cw, x3, x4, N);

    final_kernel<<<(int)((tot + 255) / 256), 256, 0, stream>>>(x1, x2, x3, x4, eu, ei,
                                                               out, NU64, NI64);
}